// Round 9
// baseline (114.627 us; speedup 1.0000x reference)
//
#include <hip/hip_runtime.h>

#define IN_CH 96
#define OUT_CH 384
#define THREADS 384

typedef float f32x4 __attribute__((ext_vector_type(4)));

// R4 mapping (4 channels/thread, f32x4 nt stores, grid 768) + R8's weight
// pinning. R7 showed VGPR=44: the compiler SANK the 48-float weight*mask
// stash back into the hot loop. The empty-asm redefinition makes each stash
// value opaque (unrematerializable), forcing true register residency.
// 52 pinned + ~30 working regs ~= 85 VGPR, fits the 102 cap of (384,5).
//
// Thread t: cg = t%96 -> channels {4cg..4cg+3} of joint cg>>2; rl = t/96 ->
// row 4q+rl. 12-float contiguous x-window (3x dwordx4; overlap L1-served),
// 48 FMAs, one f32x4 nt store (wave = 1KB contiguous, L3-bypass keeps x
// resident in L3 for the read stream).
__global__ __launch_bounds__(THREADS, 5) void skel_linear_kernel(
    const float* __restrict__ x,
    const float* __restrict__ weight,
    const float* __restrict__ mask,
    const float* __restrict__ bias,
    float* __restrict__ out,
    int batch)
{
    const int t     = threadIdx.x;
    const int cg    = t % 96;
    const int rl    = t / 96;          // 0..3
    const int chan  = cg * 4;
    const int joint = cg >> 2;
    const int jc    = (joint - 1 < 0) ? 0 : ((joint - 1 > 21) ? 21 : joint - 1);
    const int c0    = jc * 4;          // contiguous 12-col window [c0, c0+12)

    // Masked weights + bias, loaded once.
    float w[4][12];
    float b[4];
#pragma unroll
    for (int j = 0; j < 4; ++j) {
        const size_t row = (size_t)(chan + j) * IN_CH;
#pragma unroll
        for (int c = 0; c < 12; ++c)
            w[j][c] = weight[row + c0 + c] * mask[row + c0 + c];
        b[j] = bias[chan + j];
    }
    // Pin the stash in VGPRs: opaque redefinition -> no remat/sinking.
#pragma unroll
    for (int j = 0; j < 4; ++j) {
#pragma unroll
        for (int c = 0; c < 12; ++c)
            asm volatile("" : "+v"(w[j][c]));
        asm volatile("" : "+v"(b[j]));
    }

    const int nquads = batch >> 2;     // 65536 row-quads
    for (int q = blockIdx.x; q < nquads; q += gridDim.x) {
        const int row = q * 4 + rl;
        const f32x4* xv = reinterpret_cast<const f32x4*>(x + (size_t)row * IN_CH + c0);
        const f32x4 xa = xv[0];
        const f32x4 xb = xv[1];
        const f32x4 xc = xv[2];

        f32x4 o4;
#pragma unroll
        for (int j = 0; j < 4; ++j) {
            float acc = b[j];
            acc = fmaf(w[j][0],  xa.x, acc);
            acc = fmaf(w[j][1],  xa.y, acc);
            acc = fmaf(w[j][2],  xa.z, acc);
            acc = fmaf(w[j][3],  xa.w, acc);
            acc = fmaf(w[j][4],  xb.x, acc);
            acc = fmaf(w[j][5],  xb.y, acc);
            acc = fmaf(w[j][6],  xb.z, acc);
            acc = fmaf(w[j][7],  xb.w, acc);
            acc = fmaf(w[j][8],  xc.x, acc);
            acc = fmaf(w[j][9],  xc.y, acc);
            acc = fmaf(w[j][10], xc.z, acc);
            acc = fmaf(w[j][11], xc.w, acc);
            o4[j] = acc;
        }

        f32x4* dst = reinterpret_cast<f32x4*>(
            out + (size_t)row * OUT_CH + chan);
        __builtin_nontemporal_store(o4, dst);
    }
}

extern "C" void kernel_launch(void* const* d_in, const int* in_sizes, int n_in,
                              void* d_out, int out_size, void* d_ws, size_t ws_size,
                              hipStream_t stream) {
    const float* x      = (const float*)d_in[0];
    const float* weight = (const float*)d_in[1];
    const float* mask   = (const float*)d_in[2];
    const float* bias   = (const float*)d_in[3];
    float* out          = (float*)d_out;

    const int batch = in_sizes[0] / IN_CH;   // 262144
    const int grid  = 768;   // proven best (R4/R7 A/B: 768 > 1280)

    skel_linear_kernel<<<grid, THREADS, 0, stream>>>(x, weight, mask, bias, out, batch);
}

// Round 10
// 107.707 us; speedup vs baseline: 1.0642x; 1.0642x over previous
//
#include <hip/hip_runtime.h>

#define IN_CH 96
#define OUT_CH 384
#define THREADS 384

typedef float f32x4 __attribute__((ext_vector_type(4)));
typedef float f32x2 __attribute__((ext_vector_type(2)));

// R8 winner (2ch/thread, 26-float pinned stash, nt stores, grid 768) with ONE
// change: 2 rows per thread per iteration (grid-stride over row-QUADS).
// Rationale: R8 is latency-bound — per wave-iter serial chain (3 loads ~350cy
// -> 24 FMA -> store) with only 4.5 waves/SIMD. Doubling independent loads
// per iteration (6 dwordx4) halves effective latency per output row without
// adding blocks (R6 showed more blocks hurt: prologue re-pay + stagger).
// Stash stays at 26 floats — R9 proved a 52-float stash gets spilled
// (VGPR=36), R8 proved 26 is respected.
//
// Thread t: p = t%192 -> channels {2p,2p+1} of joint p>>3; rl = t/192 in
// {0,1}; rows 4q+rl and 4q+2+rl (block-iter covers the full quad).
__global__ __launch_bounds__(THREADS, 5) void skel_linear_kernel(
    const float* __restrict__ x,
    const float* __restrict__ weight,
    const float* __restrict__ mask,
    const float* __restrict__ bias,
    float* __restrict__ out,
    int batch)
{
    const int t     = threadIdx.x;
    const int p     = t % 192;         // channel-pair index 0..191
    const int rl    = t / 192;         // 0..1
    const int chan  = p * 2;
    const int joint = p >> 3;
    const int jc    = (joint - 1 < 0) ? 0 : ((joint - 1 > 21) ? 21 : joint - 1);
    const int c0    = jc * 4;          // contiguous 12-col window [c0, c0+12)

    // Masked weights + bias, loaded once (26 floats -> stays resident, cf R8).
    float w[2][12];
    float b[2];
#pragma unroll
    for (int j = 0; j < 2; ++j) {
        const size_t row = (size_t)(chan + j) * IN_CH;
#pragma unroll
        for (int c = 0; c < 12; ++c)
            w[j][c] = weight[row + c0 + c] * mask[row + c0 + c];
        b[j] = bias[chan + j];
    }
#pragma unroll
    for (int j = 0; j < 2; ++j) {
#pragma unroll
        for (int c = 0; c < 12; ++c)
            asm volatile("" : "+v"(w[j][c]));
        asm volatile("" : "+v"(b[j]));
    }

    const int nquads = batch >> 2;     // 65536 row-quads
    for (int q = blockIdx.x; q < nquads; q += gridDim.x) {
        const int r0 = q * 4 + rl;     // first row
        const int r1 = r0 + 2;         // second row (independent chain)

        const f32x4* xv0 = reinterpret_cast<const f32x4*>(x + (size_t)r0 * IN_CH + c0);
        const f32x4* xv1 = reinterpret_cast<const f32x4*>(x + (size_t)r1 * IN_CH + c0);
        const f32x4 xa0 = xv0[0], xb0 = xv0[1], xc0 = xv0[2];
        const f32x4 xa1 = xv1[0], xb1 = xv1[1], xc1 = xv1[2];

        f32x2 o0, o1;
#pragma unroll
        for (int j = 0; j < 2; ++j) {
            float a0 = b[j], a1 = b[j];
            a0 = fmaf(w[j][0],  xa0.x, a0);  a1 = fmaf(w[j][0],  xa1.x, a1);
            a0 = fmaf(w[j][1],  xa0.y, a0);  a1 = fmaf(w[j][1],  xa1.y, a1);
            a0 = fmaf(w[j][2],  xa0.z, a0);  a1 = fmaf(w[j][2],  xa1.z, a1);
            a0 = fmaf(w[j][3],  xa0.w, a0);  a1 = fmaf(w[j][3],  xa1.w, a1);
            a0 = fmaf(w[j][4],  xb0.x, a0);  a1 = fmaf(w[j][4],  xb1.x, a1);
            a0 = fmaf(w[j][5],  xb0.y, a0);  a1 = fmaf(w[j][5],  xb1.y, a1);
            a0 = fmaf(w[j][6],  xb0.z, a0);  a1 = fmaf(w[j][6],  xb1.z, a1);
            a0 = fmaf(w[j][7],  xb0.w, a0);  a1 = fmaf(w[j][7],  xb1.w, a1);
            a0 = fmaf(w[j][8],  xc0.x, a0);  a1 = fmaf(w[j][8],  xc1.x, a1);
            a0 = fmaf(w[j][9],  xc0.y, a0);  a1 = fmaf(w[j][9],  xc1.y, a1);
            a0 = fmaf(w[j][10], xc0.z, a0);  a1 = fmaf(w[j][10], xc1.z, a1);
            a0 = fmaf(w[j][11], xc0.w, a0);  a1 = fmaf(w[j][11], xc1.w, a1);
            o0[j] = a0;  o1[j] = a1;
        }

        __builtin_nontemporal_store(o0,
            reinterpret_cast<f32x2*>(out + (size_t)r0 * OUT_CH + chan));
        __builtin_nontemporal_store(o1,
            reinterpret_cast<f32x2*>(out + (size_t)r1 * OUT_CH + chan));
    }
}

extern "C" void kernel_launch(void* const* d_in, const int* in_sizes, int n_in,
                              void* d_out, int out_size, void* d_ws, size_t ws_size,
                              hipStream_t stream) {
    const float* x      = (const float*)d_in[0];
    const float* weight = (const float*)d_in[1];
    const float* mask   = (const float*)d_in[2];
    const float* bias   = (const float*)d_in[3];
    float* out          = (float*)d_out;

    const int batch = in_sizes[0] / IN_CH;   // 262144
    const int grid  = 768;   // proven best (R4/R7: 768 > 1280; R6 prologue cost)

    skel_linear_kernel<<<grid, THREADS, 0, stream>>>(x, weight, mask, bias, out, batch);
}